// Round 12
// baseline (265.897 us; speedup 1.0000x reference)
//
#include <hip/hip_runtime.h>

// Problem constants
#define B_ 2048
#define S_ 512
#define I_ 256
#define F_ 256
#define NG 8   // partial-groups for the W2 fold

// ---------------- workspace layout (floats) ----------------
#define OFF_W    0                        // w[B,F]
#define OFF_SW   (OFF_W + B_*F_)          // Sw[B]
#define OFF_RP   (OFF_SW + B_)            // rp[NG][512]
#define OFF_RH   (OFF_RP + NG*512)        // rh[256]
#define OFF_RV   (OFF_RH + 256)           // rv[256]
#define OFF_SC   (OFF_RV + 256)           // sc[2]: R, c0
#define OFF_U    531456                   // u[B,S]  (16B aligned)
#define OFF_P    (OFF_U + B_*S_)          // p[B,S]
// end = 2,628,608 floats = 10.51 MB (proven budget)

// ---------------------------------------------------------------------------
// k_pre: blocks [0,512)  : w[b,f] = hidden[b,:].W1[f,:], Sw[b] (4 batches/blk)
//        blocks [512,520): rp partial fold of r = Wfc@W2
// (byte-identical to R5)
__global__ __launch_bounds__(256) void k_pre(
    const float* __restrict__ hidden, const float* __restrict__ W1,
    const float* __restrict__ W2, const float* __restrict__ Wfc,
    float* __restrict__ ws) {
  const int tid = threadIdx.x;

  if (blockIdx.x >= B_ / 4) {
    const int g = blockIdx.x - B_ / 4;
    float acc0 = 0.f, acc1 = 0.f;
#pragma unroll 8
    for (int ii = 0; ii < 32; ++ii) {
      const int i = g * 32 + ii;
      const float f = Wfc[i];
      acc0 += f * W2[(size_t)i * (I_ + F_) + tid];
      acc1 += f * W2[(size_t)i * (I_ + F_) + tid + 256];
    }
    ws[OFF_RP + g * 512 + tid] = acc0;        // r_h partial
    ws[OFF_RP + g * 512 + 256 + tid] = acc1;  // r_v partial
    return;
  }

  __shared__ float h[4][I_];
  __shared__ float red[256];
  const int b0 = blockIdx.x * 4;
#pragma unroll
  for (int k = 0; k < 4; ++k) h[k][tid] = hidden[(size_t)(b0 + k) * I_ + tid];
  __syncthreads();

  const int f = tid;
  const float4* wrow = (const float4*)(W1 + (size_t)f * I_);
  float acc[4] = {0.f, 0.f, 0.f, 0.f};
#pragma unroll 4
  for (int iq = 0; iq < I_ / 4; ++iq) {
    const float4 v = wrow[iq];
    const int i = 4 * iq;
#pragma unroll
    for (int k = 0; k < 4; ++k)
      acc[k] += v.x * h[k][i] + v.y * h[k][i + 1] + v.z * h[k][i + 2] + v.w * h[k][i + 3];
  }
#pragma unroll
  for (int k = 0; k < 4; ++k) ws[OFF_W + (size_t)(b0 + k) * F_ + f] = acc[k];

#pragma unroll
  for (int k = 0; k < 4; ++k) {
    red[tid] = acc[k];
    __syncthreads();
    for (int s = 128; s > 0; s >>= 1) { if (tid < s) red[tid] += red[tid + s]; __syncthreads(); }
    if (tid == 0) ws[OFF_SW + b0 + k] = red[0];
    __syncthreads();
  }
}

// ---------------------------------------------------------------------------
// k_mid: one block. Fold rh[x], rv[x]; R = sum(rv); c0 = Wfc.b2 + bfc.
// (proven neutral, R11)
__global__ __launch_bounds__(256) void k_mid(
    const float* __restrict__ Wfc, const float* __restrict__ b2,
    const float* __restrict__ bfc, float* __restrict__ ws) {
  const int tid = threadIdx.x;
  const int lane = tid & 63;
  const int wid = tid >> 6;
  __shared__ float redA[4], redB[4];

  float rh = 0.f, rv = 0.f;
#pragma unroll
  for (int g = 0; g < NG; ++g) {
    rh += ws[OFF_RP + g * 512 + tid];
    rv += ws[OFF_RP + g * 512 + 256 + tid];
  }
  ws[OFF_RH + tid] = rh;
  ws[OFF_RV + tid] = rv;

  float t0 = rv, t1 = Wfc[tid] * b2[tid];
#pragma unroll
  for (int m = 32; m >= 1; m >>= 1) {
    t0 += __shfl_xor(t0, m, 64);
    t1 += __shfl_xor(t1, m, 64);
  }
  if (lane == 0) { redA[wid] = t0; redB[wid] = t1; }
  __syncthreads();
  if (tid == 0) {
    ws[OFF_SC + 0] = redA[0] + redA[1] + redA[2] + redA[3];           // R
    ws[OFF_SC + 1] = redB[0] + redB[1] + redB[2] + redB[3] + bfc[0];  // c0
  }
}

// ---------------------------------------------------------------------------
// K1 v3: deep-MLP stream. Each wave PRELOADS its 8 rows (8 KB) back-to-back
// into registers — no dependent instruction between the 8 loads — then does
// the dots and an 8-row-interleaved shfl reduce (same xor order as R5:
// bitwise-identical u,p). Geometry identical to R5: grid (16,B), 4 waves,
// 32 rows/block.
__global__ __launch_bounds__(256) void k1_scan(
    const float* __restrict__ inp, const float* __restrict__ wsw,
    const float* __restrict__ wsrv,
    float* __restrict__ wsu, float* __restrict__ wsp) {
  const int b = blockIdx.y;
  const int t0 = blockIdx.x * 32;
  const int tid = threadIdx.x;
  const int lane = tid & 63;
  const int wid = tid >> 6;

  const float4 w4  = ((const float4*)(wsw + (size_t)b * F_))[lane];  // L2 hit
  const float4 rv4 = ((const float4*)wsrv)[lane];                    // L2 hit
  const float* base = inp + ((size_t)b * S_ + t0) * I_;
  float* uo = wsu + (size_t)b * S_ + t0;
  float* po = wsp + (size_t)b * S_ + t0;

  // ---- phase 1: 8 independent 1KB loads per wave (8 KB in flight) ----
  float4 r[8];
#pragma unroll
  for (int rr = 0; rr < 8; ++rr)
    r[rr] = ((const float4*)(base + (size_t)(wid + 4 * rr) * I_))[lane];

  // ---- phase 2: dots ----
  float du[8], dp[8];
#pragma unroll
  for (int rr = 0; rr < 8; ++rr) {
    du[rr] = r[rr].x * w4.x + r[rr].y * w4.y + r[rr].z * w4.z + r[rr].w * w4.w;
    dp[rr] = r[rr].x * rv4.x + r[rr].y * rv4.y + r[rr].z * rv4.z + r[rr].w * rv4.w;
  }

  // ---- phase 3: interleaved reduce (16 independent chains/step) ----
#pragma unroll
  for (int m = 32; m >= 1; m >>= 1) {
#pragma unroll
    for (int rr = 0; rr < 8; ++rr) {
      du[rr] += __shfl_xor(du[rr], m, 64);
      dp[rr] += __shfl_xor(dp[rr], m, 64);
    }
  }

  if (lane == 0) {
#pragma unroll
    for (int rr = 0; rr < 8; ++rr) {
      uo[wid + 4 * rr] = du[rr];
      po[wid + 4 * rr] = dp[rr];
    }
  }
}

// ---------------------------------------------------------------------------
// K2: per-batch epilogue — byte-identical to R5 (LDS-staged u,p; per-thread
// Wc row; own fold of r partials).
__global__ __launch_bounds__(256) void k2_epilogue(
    const float* __restrict__ Wc, const float* __restrict__ bc,
    const float* __restrict__ b2, const float* __restrict__ Wfc,
    const float* __restrict__ bfc, const float* __restrict__ hidden,
    const float* __restrict__ wsu, const float* __restrict__ wsp,
    const float* __restrict__ wsSw, const float* __restrict__ wsrp,
    float* __restrict__ out) {
  const int b0 = blockIdx.x * 4;
  const int tid = threadIdx.x;
  const int lane = tid & 63;
  const int wid = tid >> 6;
  __shared__ float u[4][S_];
  __shared__ float p[4][S_];
  __shared__ float redA[4], redB[4];
  __shared__ float wred[4][4];

  float rh = 0.f, rv = 0.f;
#pragma unroll
  for (int g = 0; g < NG; ++g) {
    rh += wsrp[g * 512 + tid];
    rv += wsrp[g * 512 + 256 + tid];
  }
  float t0 = rv, t1 = Wfc[tid] * b2[tid];
#pragma unroll
  for (int m = 32; m >= 1; m >>= 1) {
    t0 += __shfl_xor(t0, m, 64);
    t1 += __shfl_xor(t1, m, 64);
  }
  if (lane == 0) { redA[wid] = t0; redB[wid] = t1; }

#pragma unroll
  for (int k = 0; k < 4; ++k) {
    u[k][tid]       = wsu[(size_t)(b0 + k) * S_ + tid];
    u[k][tid + 256] = wsu[(size_t)(b0 + k) * S_ + tid + 256];
    p[k][tid]       = wsp[(size_t)(b0 + k) * S_ + tid];
    p[k][tid + 256] = wsp[(size_t)(b0 + k) * S_ + tid + 256];
  }
  __syncthreads();

  const float R  = redA[0] + redA[1] + redA[2] + redA[3];
  const float c0 = redB[0] + redB[1] + redB[2] + redB[3] + bfc[0];

  const int x = tid;
  const float4* wrow = (const float4*)(Wc + (size_t)x * S_);
  float ss[4] = {0.f, 0.f, 0.f, 0.f};
  float qs[4] = {0.f, 0.f, 0.f, 0.f};
#pragma unroll 4
  for (int tq = 0; tq < S_ / 4; ++tq) {
    const float4 v = wrow[tq];
    const int t = 4 * tq;
#pragma unroll
    for (int k = 0; k < 4; ++k) {
      ss[k] += v.x * u[k][t] + v.y * u[k][t + 1] + v.z * u[k][t + 2] + v.w * u[k][t + 3];
      qs[k] += v.x * p[k][t] + v.y * p[k][t + 1] + v.z * p[k][t + 2] + v.w * p[k][t + 3];
    }
  }

  const float bcx = bc[x];
#pragma unroll
  for (int k = 0; k < 4; ++k) {
    const float Sw = wsSw[b0 + k];
    const float s = ss[k] + bcx * Sw;
    const float a = 1.f / (1.f + expf(-s));
    float partial = a * (qs[k] + bcx * R) + rh * hidden[(size_t)(b0 + k) * I_ + x];
#pragma unroll
    for (int m = 32; m >= 1; m >>= 1) partial += __shfl_xor(partial, m, 64);
    if (lane == 0) wred[k][wid] = partial;
  }
  __syncthreads();
  if (tid < 4)
    out[b0 + tid] = wred[tid][0] + wred[tid][1] + wred[tid][2] + wred[tid][3] + c0;
}

// ---------------------------------------------------------------------------
extern "C" void kernel_launch(void* const* d_in, const int* in_sizes, int n_in,
                              void* d_out, int out_size, void* d_ws, size_t ws_size,
                              hipStream_t stream) {
  (void)in_sizes; (void)n_in; (void)out_size; (void)ws_size;
  const float* hidden = (const float*)d_in[0];
  const float* inp    = (const float*)d_in[1];
  const float* W1     = (const float*)d_in[2];
  const float* Wc     = (const float*)d_in[3];
  const float* bc     = (const float*)d_in[4];
  const float* W2     = (const float*)d_in[5];
  const float* b2     = (const float*)d_in[6];
  const float* Wfc    = (const float*)d_in[7];
  const float* bfc    = (const float*)d_in[8];
  float* out = (float*)d_out;
  float* ws  = (float*)d_ws;

  hipLaunchKernelGGL(k_pre, dim3(B_ / 4 + NG), dim3(256), 0, stream,
                     hidden, W1, W2, Wfc, ws);
  hipLaunchKernelGGL(k_mid, dim3(1), dim3(256), 0, stream, Wfc, b2, bfc, ws);
  hipLaunchKernelGGL(k1_scan, dim3(S_ / 32, B_), dim3(256), 0, stream,
                     inp, ws + OFF_W, ws + OFF_RV, ws + OFF_U, ws + OFF_P);
  hipLaunchKernelGGL(k2_epilogue, dim3(B_ / 4), dim3(256), 0, stream,
                     Wc, bc, b2, Wfc, bfc, hidden,
                     ws + OFF_U, ws + OFF_P, ws + OFF_SW, ws + OFF_RP, out);
}